// Round 13
// baseline (1684.688 us; speedup 1.0000x reference)
//
#include <hip/hip_runtime.h>
#include <hip/hip_bf16.h>
#include <hip/hip_fp16.h>

// SVD-RNN: W = U diag(s) V from Householder chains; h_t = tanh(xp_t + W h_{t-1});
// out_t = h_t W_out^T + b_out.
#define BB 64
#define TT 2048
#define II 128
#define HH 256
#define OO 128
#define RCH 8                      // recurrence chunk length (global I/O batching)

typedef _Float16 f16x2 __attribute__((ext_vector_type(2)));
typedef _Float16 f16x8 __attribute__((ext_vector_type(8)));
typedef float f32x4 __attribute__((ext_vector_type(4)));

#if __has_builtin(__builtin_amdgcn_fdot2)
__device__ __forceinline__ float fdot2(f16x2 a, f16x2 b, float c) {
    return __builtin_amdgcn_fdot2(a, b, c, false);
}
#else
__device__ __forceinline__ float fdot2(f16x2 a, f16x2 b, float c) {
    return fmaf((float)a.x, (float)b.x, fmaf((float)a.y, (float)b.y, c));
}
#endif

__device__ __forceinline__ f16x2 u2h(unsigned int u) { return __builtin_bit_cast(f16x2, u); }
__device__ __forceinline__ unsigned int packf16(float a, float b) {
    return __builtin_bit_cast(unsigned int, f16x2{(_Float16)a, (_Float16)b});
}

__device__ __forceinline__ float tanh_fast(float x) {
    float xc = fminf(fmaxf(x, -9.0f), 9.0f);
    float e = __expf(2.0f * xc);
    return (e - 1.0f) * __fdividef(1.0f, e + 1.0f);
}

// lgkm-only workgroup barrier: orders LDS writes/reads across waves WITHOUT
// draining vmcnt, so chunked global prefetch/stores stay in flight across
// steps (stock __syncthreads emits s_waitcnt vmcnt(0) expcnt(0) lgkmcnt(0)
// which would expose the xp-prefetch HBM latency once per chunk).
__device__ __forceinline__ void step_barrier() {
    __builtin_amdgcn_sched_barrier(0);
    asm volatile("s_waitcnt lgkmcnt(0)" ::: "memory");
    __builtin_amdgcn_s_barrier();
    __builtin_amdgcn_sched_barrier(0);
}

// ---------------------------------------------------------------------------
// Kernel 1: masked+flipped Householder vectors and betas.
// ---------------------------------------------------------------------------
__global__ __launch_bounds__(64) void prep_kernel(
    const float* __restrict__ u_raw, const float* __restrict__ v_raw,
    float* __restrict__ u_eff, float* __restrict__ v_eff,
    float* __restrict__ beta_u, float* __restrict__ beta_v)
{
    const int row = blockIdx.x;
    const int lane = threadIdx.x;
    const bool isU = row < HH;
    const int i = isU ? row : row - HH;
    const float* src = isU ? (u_raw + (size_t)i * HH) : (v_raw + (size_t)(HH - 1 - i) * HH);
    float* dst = (isU ? u_eff : v_eff) + (size_t)i * HH;
    const int lo = isU ? (HH - 1 - i) : i;
    float ss = 0.0f;
    for (int c = lane; c < HH; c += 64) {
        float vv = (c >= lo) ? src[HH - 1 - c] : 0.0f;
        dst[c] = vv;
        ss += vv * vv;
    }
    for (int m = 1; m < 64; m <<= 1) ss += __shfl_xor(ss, m, 64);
    if (lane == 0) (isU ? beta_u : beta_v)[i] = 2.0f / ss;
}

// ---------------------------------------------------------------------------
// Kernel 2: Householder chain per column.
// ---------------------------------------------------------------------------
__global__ __launch_bounds__(256) void hh_kernel(
    const float* __restrict__ u_eff, const float* __restrict__ v_eff,
    const float* __restrict__ beta_u, const float* __restrict__ beta_v,
    float* __restrict__ Ucol, float* __restrict__ Vrow)
{
    const int wid = blockIdx.x * 4 + (threadIdx.x >> 6);
    const int lane = threadIdx.x & 63;
    const bool isU = wid < HH;
    const int j = isU ? wid : wid - HH;
    const float* eff = isU ? u_eff : v_eff;
    const float* beta = isU ? beta_u : beta_v;

    float cr0 = (j == 4 * lane + 0) ? 1.0f : 0.0f;
    float cr1 = (j == 4 * lane + 1) ? 1.0f : 0.0f;
    float cr2 = (j == 4 * lane + 2) ? 1.0f : 0.0f;
    float cr3 = (j == 4 * lane + 3) ? 1.0f : 0.0f;

    const int i0 = isU ? (HH - 1 - j) : 0;
    for (int i = i0; i < HH; ++i) {
        const float4 v4 = *(const float4*)(eff + (size_t)i * HH + lane * 4);
        float d = v4.x * cr0 + v4.y * cr1 + v4.z * cr2 + v4.w * cr3;
        for (int m = 1; m < 64; m <<= 1) d += __shfl_xor(d, m, 64);
        const float t = beta[i] * d;
        cr0 = fmaf(-t, v4.x, cr0);
        cr1 = fmaf(-t, v4.y, cr1);
        cr2 = fmaf(-t, v4.z, cr2);
        cr3 = fmaf(-t, v4.w, cr3);
    }
    if (isU) {
        *(float4*)(Ucol + (size_t)j * HH + lane * 4) = make_float4(cr0, cr1, cr2, cr3);
    } else {
        Vrow[(size_t)(4 * lane + 0) * HH + j] = cr0;
        Vrow[(size_t)(4 * lane + 1) * HH + j] = cr1;
        Vrow[(size_t)(4 * lane + 2) * HH + j] = cr2;
        Vrow[(size_t)(4 * lane + 3) * HH + j] = cr3;
    }
}

// ---------------------------------------------------------------------------
// Kernel 3: W[r][c] = sum_k Ucol[k][r] * sig[k] * Vrow[k][c]
// ---------------------------------------------------------------------------
__global__ __launch_bounds__(256) void w_kernel(
    const float* __restrict__ Ucol, const float* __restrict__ Vrow,
    const float* __restrict__ sig, float* __restrict__ Wm)
{
    const int r = blockIdx.x;
    const int c = threadIdx.x;
    float acc = 0.0f;
    #pragma unroll 4
    for (int k = 0; k < HH; ++k) {
        acc = fmaf(Ucol[(size_t)k * HH + r] * sig[k], Vrow[(size_t)k * HH + c], acc);
    }
    Wm[(size_t)r * HH + c] = acc;
}

// ---------------------------------------------------------------------------
// MFMA tiled GEMM with bias: C[M][N] = A[M][K] * B[N][K]^T + bias[N].
// BM=128, BN=64, BK=32; 256 threads = 4 waves, each wave a 64x32 quadrant
// (4 m-tiles x 2 n-tiles of 16x16, mfma_f32_16x16x32_f16).
// ---------------------------------------------------------------------------
__device__ __forceinline__ void stage16(_Float16* dst, const float* src) {
    #pragma unroll
    for (int i = 0; i < 4; ++i) {
        float4 f = ((const float4*)src)[i];
        ((f16x2*)dst)[2 * i + 0] = f16x2{(_Float16)f.x, (_Float16)f.y};
        ((f16x2*)dst)[2 * i + 1] = f16x2{(_Float16)f.z, (_Float16)f.w};
    }
}
__device__ __forceinline__ void stage16(_Float16* dst, const __half* src) {
    ((uint4*)dst)[0] = ((const uint4*)src)[0];
    ((uint4*)dst)[1] = ((const uint4*)src)[1];
}
__device__ __forceinline__ void storeC(float* p, float v) { *p = v; }
__device__ __forceinline__ void storeC(__half* p, float v) { *p = __float2half_rn(v); }

template <typename AT, typename OT>
__global__ __launch_bounds__(256) void gemm_mfma(
    const AT* __restrict__ A, const float* __restrict__ Bm,
    const float* __restrict__ bias, OT* __restrict__ C,
    int M, int N, int K)
{
    __shared__ _Float16 As[128][40];
    __shared__ _Float16 Bs[64][40];
    const int tid = threadIdx.x;
    const int m0 = blockIdx.x * 128;
    const int n0 = blockIdx.y * 64;
    const int lane = tid & 63;
    const int w = tid >> 6;
    const int lo = lane & 15;
    const int qd = lane >> 4;
    const int mh = w >> 1;               // m-half (64 rows)
    const int nh = w & 1;                // n-half (32 cols)
    const int srow = tid >> 1;           // staging row 0..127
    const int shalf = tid & 1;           // 16-f16 half of the 32-k row

    f32x4 acc[4][2] = {};
    for (int k0 = 0; k0 < K; k0 += 32) {
        stage16(&As[srow][shalf * 16], A + (size_t)(m0 + srow) * K + k0 + shalf * 16);
        if (tid < 128)
            stage16(&Bs[srow][shalf * 16], Bm + (size_t)(n0 + srow) * K + k0 + shalf * 16);
        __syncthreads();
        f16x8 af[4], bf[2];
        #pragma unroll
        for (int mt = 0; mt < 4; ++mt)
            af[mt] = *(const f16x8*)&As[64 * mh + 16 * mt + lo][qd * 8];
        #pragma unroll
        for (int nt = 0; nt < 2; ++nt)
            bf[nt] = *(const f16x8*)&Bs[32 * nh + 16 * nt + lo][qd * 8];
        #pragma unroll
        for (int mt = 0; mt < 4; ++mt)
            #pragma unroll
            for (int nt = 0; nt < 2; ++nt)
                acc[mt][nt] = __builtin_amdgcn_mfma_f32_16x16x32_f16(
                    af[mt], bf[nt], acc[mt][nt], 0, 0, 0);
        __syncthreads();
    }
    #pragma unroll
    for (int nt = 0; nt < 2; ++nt) {
        const int n = n0 + 32 * nh + 16 * nt + lo;
        const float bv = bias[n];
        #pragma unroll
        for (int mt = 0; mt < 4; ++mt) {
            const int m = m0 + 64 * mh + 16 * mt + 4 * qd;
            #pragma unroll
            for (int r = 0; r < 4; ++r)
                storeC(C + (size_t)(m + r) * N + n, acc[mt][nt][r] + bv);
        }
    }
}

// ---------------------------------------------------------------------------
// Kernel 5: recurrence — SHUFFLE-REDUCE, one LDS round-trip per step.
// 64 WGs x 256 threads (4 waves). R11 post-mortem: 1092us = 1280cy/step,
// ~640cy issue + ~640cy unhidden latency; the chain paid TWO LDS
// round-trips (ps and hx) plus ~150 instrs of ps-reduce issue. This shape
// keeps all 4 k-slices of a row IN ONE WAVE so the k-reduction is an
// in-register butterfly (no ps buffer at all):
//  * wave q owns rows [64q,64q+64). Lane l computes rows 64q+4*(l&15)+j
//    (j=0..3) over k-slice [64*(l>>4), +64): 128 fdot2/lane (4 ILP chains,
//    256cy issue = the MAC floor for 1 CU).
//  * k-reduce: __shfl_xor(16) + __shfl_xor(32) per row (8 shfl + 8 add) —
//    lanes l, l+16, l+32, l+48 hold the 4 partials of the same rows.
//  * h exchange (the only cross-wave data): lanes<16 write their 4-row
//    pack (b64) to hx[p^1]; ONE lgkm-only barrier; next step all waves
//    read their 64-elem slice from hx[p^1] (8 x b128, 16-lane broadcast,
//    conflict-free). hx DOUBLE-BUFFERED (1 KB): readers of hx[p] may lag
//    writers of hx[p^1]; buffer p is rewritten only at step s+1, after the
//    step-s barrier drained all step-s reads of p.
//  * per-step chain: barrier + hx read(~130) + dot(~260) + shfl(~80) +
//    tanh(~40) + write(~30) ~= 640cy vs 1280 measured in R11.
// R1: no h read amplification (broadcast b128). R2: no added work at same
// barriers. R3: no redundant phase2 (4 groups compute same rows, only
// lanes<16 store). R8: coverage = 4 waves x 64 rows x full k via shuffle.
// R9: operand pairing via clean m-loop, no hand-unroll typos.
// ---------------------------------------------------------------------------
__global__ __launch_bounds__(256, 1) void recur_kernel(
    const float* __restrict__ Wm,              // [256][256] f32 row-major
    const __half* __restrict__ xp,             // [B][T][256] f16
    __half* __restrict__ hall)                 // [B][T][256] f16
{
    const int b = blockIdx.x;
    const int tid = threadIdx.x;
    const int l = tid & 63;
    const int q = tid >> 6;        // wave 0..3
    const int lr = l & 15;         // row group within wave
    const int kh = l >> 4;         // k-slice 0..3

    __shared__ __align__(16) _Float16 hx[2][HH];      // dbuf packed h, 1 KB

    const int base_row = 64 * q + 4 * lr;             // this lane's 4 rows

    // W fragment: rows base_row..+3, cols [64*kh, 64*kh+64) (128 VGPRs).
    f16x2 w2[4][32];
    #pragma unroll
    for (int j = 0; j < 4; ++j) {
        const float* Wp = Wm + (size_t)(base_row + j) * HH + 64 * kh;
        #pragma unroll
        for (int c4 = 0; c4 < 16; ++c4) {
            float4 f = *(const float4*)(Wp + 4 * c4);
            w2[j][2 * c4 + 0] = f16x2{(_Float16)f.x, (_Float16)f.y};
            w2[j][2 * c4 + 1] = f16x2{(_Float16)f.z, (_Float16)f.w};
        }
    }
    if (tid < HH / 2) {                                // zero hx[0] (step 0 reads it)
        ((unsigned int*)&hx[0][0])[tid] = 0u;
    }
    __syncthreads();

    // Global I/O: 4 f16 (8 B) per lane at base_row; groups kh>0 load the
    // same addresses (L1 broadcast), only kh==0 stores.
    const uint2* xpw = (const uint2*)((const _Float16*)xp + (size_t)b * TT * HH + base_row);
    uint2* hw = (uint2*)((_Float16*)hall + (size_t)b * TT * HH + base_row);
    const bool st = (kh == 0);

    uint2 xpc[RCH], xpn[RCH], hst[RCH];
    #pragma unroll
    for (int s = 0; s < RCH; ++s) xpc[s] = xpw[(size_t)s * (HH / 4)];

    const int nch = TT / RCH;
    for (int c = 0; c < nch; ++c) {
        if (c + 1 < nch) {
            const uint2* xn = xpw + (size_t)(c + 1) * RCH * (HH / 4);
            #pragma unroll
            for (int s = 0; s < RCH; ++s) xpn[s] = xn[(size_t)s * (HH / 4)];
        }
        #pragma unroll
        for (int s = 0; s < RCH; ++s) {
            const int p = s & 1;
            // --- dot: own k-slice from hx[p] (broadcast b128 reads) ---
            const uint4* hbp = (const uint4*)&hx[p][64 * kh];
            uint4 hb[8];
            #pragma unroll
            for (int g = 0; g < 8; ++g) hb[g] = hbp[g];
            float a0 = 0.f, a1 = 0.f, a2 = 0.f, a3 = 0.f;
            #pragma unroll
            for (int g = 0; g < 8; ++g) {
                const f16x2 hp0 = u2h(hb[g].x), hp1 = u2h(hb[g].y);
                const f16x2 hp2 = u2h(hb[g].z), hp3 = u2h(hb[g].w);
                a0 = fdot2(w2[0][4 * g + 0], hp0, a0);
                a1 = fdot2(w2[1][4 * g + 0], hp0, a1);
                a2 = fdot2(w2[2][4 * g + 0], hp0, a2);
                a3 = fdot2(w2[3][4 * g + 0], hp0, a3);
                a0 = fdot2(w2[0][4 * g + 1], hp1, a0);
                a1 = fdot2(w2[1][4 * g + 1], hp1, a1);
                a2 = fdot2(w2[2][4 * g + 1], hp1, a2);
                a3 = fdot2(w2[3][4 * g + 1], hp1, a3);
                a0 = fdot2(w2[0][4 * g + 2], hp2, a0);
                a1 = fdot2(w2[1][4 * g + 2], hp2, a1);
                a2 = fdot2(w2[2][4 * g + 2], hp2, a2);
                a3 = fdot2(w2[3][4 * g + 2], hp2, a3);
                a0 = fdot2(w2[0][4 * g + 3], hp3, a0);
                a1 = fdot2(w2[1][4 * g + 3], hp3, a1);
                a2 = fdot2(w2[2][4 * g + 3], hp3, a2);
                a3 = fdot2(w2[3][4 * g + 3], hp3, a3);
            }
            // --- k-reduce: butterfly over the 4 slice groups (lane^16,^32) ---
            a0 += __shfl_xor(a0, 16, 64);  a0 += __shfl_xor(a0, 32, 64);
            a1 += __shfl_xor(a1, 16, 64);  a1 += __shfl_xor(a1, 32, 64);
            a2 += __shfl_xor(a2, 16, 64);  a2 += __shfl_xor(a2, 32, 64);
            a3 += __shfl_xor(a3, 16, 64);  a3 += __shfl_xor(a3, 32, 64);
            // --- tanh + pack (all lanes redundantly; identical values) ---
            const f16x2 xlo = u2h(xpc[s].x), xhi = u2h(xpc[s].y);
            const float h0 = tanh_fast(a0 + (float)xlo.x);
            const float h1 = tanh_fast(a1 + (float)xlo.y);
            const float h2 = tanh_fast(a2 + (float)xhi.x);
            const float h3 = tanh_fast(a3 + (float)xhi.y);
            const unsigned int u0 = packf16(h0, h1);
            const unsigned int u1 = packf16(h2, h3);
            hst[s] = make_uint2(u0, u1);
            if (st) *(uint2*)&hx[p ^ 1][base_row] = make_uint2(u0, u1);
            step_barrier();
        }
        if (st) {
            uint2* hwc = hw + (size_t)c * RCH * (HH / 4);
            #pragma unroll
            for (int s2 = 0; s2 < RCH; ++s2) hwc[(size_t)s2 * (HH / 4)] = hst[s2];
        }
        #pragma unroll
        for (int s2 = 0; s2 < RCH; ++s2) xpc[s2] = xpn[s2];
    }
}

// ---------------------------------------------------------------------------
extern "C" void kernel_launch(void* const* d_in, const int* in_sizes, int n_in,
                              void* d_out, int out_size, void* d_ws, size_t ws_size,
                              hipStream_t stream) {
    const float* x     = (const float*)d_in[0];   // [B][T][I]
    const float* W_in  = (const float*)d_in[1];   // [H][I]
    const float* b_in  = (const float*)d_in[2];   // [H]
    const float* W_out = (const float*)d_in[3];   // [O][H]
    const float* b_out = (const float*)d_in[4];   // [O]
    const float* u_raw = (const float*)d_in[5];   // [M][H]
    const float* sig   = (const float*)d_in[6];   // [H]
    const float* v_raw = (const float*)d_in[7];   // [M][H]
    float* out = (float*)d_out;                   // [B][T][O]

    char* ws = (char*)d_ws;
    size_t off = 0;
    auto alloc = [&](size_t bytes) -> void* {
        void* p = (void*)(ws + off);
        off += (bytes + 255) & ~((size_t)255);
        return p;
    };
    float* u_eff  = (float*)alloc((size_t)HH * HH * 4);
    float* v_eff  = (float*)alloc((size_t)HH * HH * 4);
    float* beta_u = (float*)alloc((size_t)HH * 4);
    float* beta_v = (float*)alloc((size_t)HH * 4);
    float* Ucol   = (float*)alloc((size_t)HH * HH * 4);
    float* Vrow   = (float*)alloc((size_t)HH * HH * 4);
    float* Wm     = (float*)alloc((size_t)HH * HH * 4);
    __half* xpbuf = (__half*)alloc((size_t)BB * TT * HH * 2);
    __half* hall  = (__half*)alloc((size_t)BB * TT * HH * 2);
    (void)ws_size; (void)in_sizes; (void)n_in; (void)out_size;

    prep_kernel<<<2 * HH, 64, 0, stream>>>(u_raw, v_raw, u_eff, v_eff, beta_u, beta_v);
    hh_kernel<<<(2 * HH) / 4, 256, 0, stream>>>(u_eff, v_eff, beta_u, beta_v, Ucol, Vrow);
    w_kernel<<<HH, HH, 0, stream>>>(Ucol, Vrow, sig, Wm);
    gemm_mfma<float, __half>
        <<<dim3((BB * TT) / 128, HH / 64), 256, 0, stream>>>(x, W_in, b_in, xpbuf, BB * TT, HH, II);
    recur_kernel<<<BB, 256, 0, stream>>>(Wm, xpbuf, hall);
    gemm_mfma<__half, float>
        <<<dim3((BB * TT) / 128, OO / 64), 256, 0, stream>>>(hall, W_out, b_out, out, BB * TT, OO, HH);
}

// Round 16
// 1363.186 us; speedup vs baseline: 1.2358x; 1.2358x over previous
//
#include <hip/hip_runtime.h>
#include <hip/hip_bf16.h>
#include <hip/hip_fp16.h>

// SVD-RNN: W = U diag(s) V from Householder chains; h_t = tanh(xp_t + W h_{t-1});
// out_t = h_t W_out^T + b_out.
#define BB 64
#define TT 2048
#define II 128
#define HH 256
#define OO 128
#define RCH 8                      // recurrence chunk length (global I/O batching)

typedef _Float16 f16x2 __attribute__((ext_vector_type(2)));
typedef _Float16 f16x8 __attribute__((ext_vector_type(8)));
typedef float f32x4 __attribute__((ext_vector_type(4)));

#if __has_builtin(__builtin_amdgcn_fdot2)
__device__ __forceinline__ float fdot2(f16x2 a, f16x2 b, float c) {
    return __builtin_amdgcn_fdot2(a, b, c, false);
}
#else
__device__ __forceinline__ float fdot2(f16x2 a, f16x2 b, float c) {
    return fmaf((float)a.x, (float)b.x, fmaf((float)a.y, (float)b.y, c));
}
#endif

__device__ __forceinline__ f16x2 u2h(unsigned int u) { return __builtin_bit_cast(f16x2, u); }
__device__ __forceinline__ unsigned int packf16(float a, float b) {
    return __builtin_bit_cast(unsigned int, f16x2{(_Float16)a, (_Float16)b});
}

__device__ __forceinline__ float tanh_fast(float x) {
    float xc = fminf(fmaxf(x, -9.0f), 9.0f);
    float e = __expf(2.0f * xc);
    return (e - 1.0f) * __fdividef(1.0f, e + 1.0f);
}

// lgkm-only workgroup barrier: orders LDS writes/reads across waves WITHOUT
// draining vmcnt, so chunked global prefetch/stores stay in flight across
// steps (stock __syncthreads emits s_waitcnt vmcnt(0) expcnt(0) lgkmcnt(0)
// which would expose the xp-prefetch HBM latency once per chunk).
__device__ __forceinline__ void step_barrier() {
    __builtin_amdgcn_sched_barrier(0);
    asm volatile("s_waitcnt lgkmcnt(0)" ::: "memory");
    __builtin_amdgcn_s_barrier();
    __builtin_amdgcn_sched_barrier(0);
}

// ---------------------------------------------------------------------------
// Kernel 1: masked+flipped Householder vectors and betas.
// ---------------------------------------------------------------------------
__global__ __launch_bounds__(64) void prep_kernel(
    const float* __restrict__ u_raw, const float* __restrict__ v_raw,
    float* __restrict__ u_eff, float* __restrict__ v_eff,
    float* __restrict__ beta_u, float* __restrict__ beta_v)
{
    const int row = blockIdx.x;
    const int lane = threadIdx.x;
    const bool isU = row < HH;
    const int i = isU ? row : row - HH;
    const float* src = isU ? (u_raw + (size_t)i * HH) : (v_raw + (size_t)(HH - 1 - i) * HH);
    float* dst = (isU ? u_eff : v_eff) + (size_t)i * HH;
    const int lo = isU ? (HH - 1 - i) : i;
    float ss = 0.0f;
    for (int c = lane; c < HH; c += 64) {
        float vv = (c >= lo) ? src[HH - 1 - c] : 0.0f;
        dst[c] = vv;
        ss += vv * vv;
    }
    for (int m = 1; m < 64; m <<= 1) ss += __shfl_xor(ss, m, 64);
    if (lane == 0) (isU ? beta_u : beta_v)[i] = 2.0f / ss;
}

// ---------------------------------------------------------------------------
// Kernel 2: Householder chain per column.
// ---------------------------------------------------------------------------
__global__ __launch_bounds__(256) void hh_kernel(
    const float* __restrict__ u_eff, const float* __restrict__ v_eff,
    const float* __restrict__ beta_u, const float* __restrict__ beta_v,
    float* __restrict__ Ucol, float* __restrict__ Vrow)
{
    const int wid = blockIdx.x * 4 + (threadIdx.x >> 6);
    const int lane = threadIdx.x & 63;
    const bool isU = wid < HH;
    const int j = isU ? wid : wid - HH;
    const float* eff = isU ? u_eff : v_eff;
    const float* beta = isU ? beta_u : beta_v;

    float cr0 = (j == 4 * lane + 0) ? 1.0f : 0.0f;
    float cr1 = (j == 4 * lane + 1) ? 1.0f : 0.0f;
    float cr2 = (j == 4 * lane + 2) ? 1.0f : 0.0f;
    float cr3 = (j == 4 * lane + 3) ? 1.0f : 0.0f;

    const int i0 = isU ? (HH - 1 - j) : 0;
    for (int i = i0; i < HH; ++i) {
        const float4 v4 = *(const float4*)(eff + (size_t)i * HH + lane * 4);
        float d = v4.x * cr0 + v4.y * cr1 + v4.z * cr2 + v4.w * cr3;
        for (int m = 1; m < 64; m <<= 1) d += __shfl_xor(d, m, 64);
        const float t = beta[i] * d;
        cr0 = fmaf(-t, v4.x, cr0);
        cr1 = fmaf(-t, v4.y, cr1);
        cr2 = fmaf(-t, v4.z, cr2);
        cr3 = fmaf(-t, v4.w, cr3);
    }
    if (isU) {
        *(float4*)(Ucol + (size_t)j * HH + lane * 4) = make_float4(cr0, cr1, cr2, cr3);
    } else {
        Vrow[(size_t)(4 * lane + 0) * HH + j] = cr0;
        Vrow[(size_t)(4 * lane + 1) * HH + j] = cr1;
        Vrow[(size_t)(4 * lane + 2) * HH + j] = cr2;
        Vrow[(size_t)(4 * lane + 3) * HH + j] = cr3;
    }
}

// ---------------------------------------------------------------------------
// Kernel 3: W[r][c] = sum_k Ucol[k][r] * sig[k] * Vrow[k][c]
// ---------------------------------------------------------------------------
__global__ __launch_bounds__(256) void w_kernel(
    const float* __restrict__ Ucol, const float* __restrict__ Vrow,
    const float* __restrict__ sig, float* __restrict__ Wm)
{
    const int r = blockIdx.x;
    const int c = threadIdx.x;
    float acc = 0.0f;
    #pragma unroll 4
    for (int k = 0; k < HH; ++k) {
        acc = fmaf(Ucol[(size_t)k * HH + r] * sig[k], Vrow[(size_t)k * HH + c], acc);
    }
    Wm[(size_t)r * HH + c] = acc;
}

// ---------------------------------------------------------------------------
// MFMA tiled GEMM with bias: C[M][N] = A[M][K] * B[N][K]^T + bias[N].
// BM=128, BN=64, BK=32; 256 threads = 4 waves, each wave a 64x32 quadrant
// (4 m-tiles x 2 n-tiles of 16x16, mfma_f32_16x16x32_f16).
// ---------------------------------------------------------------------------
__device__ __forceinline__ void stage16(_Float16* dst, const float* src) {
    #pragma unroll
    for (int i = 0; i < 4; ++i) {
        float4 f = ((const float4*)src)[i];
        ((f16x2*)dst)[2 * i + 0] = f16x2{(_Float16)f.x, (_Float16)f.y};
        ((f16x2*)dst)[2 * i + 1] = f16x2{(_Float16)f.z, (_Float16)f.w};
    }
}
__device__ __forceinline__ void stage16(_Float16* dst, const __half* src) {
    ((uint4*)dst)[0] = ((const uint4*)src)[0];
    ((uint4*)dst)[1] = ((const uint4*)src)[1];
}
__device__ __forceinline__ void storeC(float* p, float v) { *p = v; }
__device__ __forceinline__ void storeC(__half* p, float v) { *p = __float2half_rn(v); }

template <typename AT, typename OT>
__global__ __launch_bounds__(256) void gemm_mfma(
    const AT* __restrict__ A, const float* __restrict__ Bm,
    const float* __restrict__ bias, OT* __restrict__ C,
    int M, int N, int K)
{
    __shared__ _Float16 As[128][40];
    __shared__ _Float16 Bs[64][40];
    const int tid = threadIdx.x;
    const int m0 = blockIdx.x * 128;
    const int n0 = blockIdx.y * 64;
    const int lane = tid & 63;
    const int w = tid >> 6;
    const int lo = lane & 15;
    const int qd = lane >> 4;
    const int mh = w >> 1;               // m-half (64 rows)
    const int nh = w & 1;                // n-half (32 cols)
    const int srow = tid >> 1;           // staging row 0..127
    const int shalf = tid & 1;           // 16-f16 half of the 32-k row

    f32x4 acc[4][2] = {};
    for (int k0 = 0; k0 < K; k0 += 32) {
        stage16(&As[srow][shalf * 16], A + (size_t)(m0 + srow) * K + k0 + shalf * 16);
        if (tid < 128)
            stage16(&Bs[srow][shalf * 16], Bm + (size_t)(n0 + srow) * K + k0 + shalf * 16);
        __syncthreads();
        f16x8 af[4], bf[2];
        #pragma unroll
        for (int mt = 0; mt < 4; ++mt)
            af[mt] = *(const f16x8*)&As[64 * mh + 16 * mt + lo][qd * 8];
        #pragma unroll
        for (int nt = 0; nt < 2; ++nt)
            bf[nt] = *(const f16x8*)&Bs[32 * nh + 16 * nt + lo][qd * 8];
        #pragma unroll
        for (int mt = 0; mt < 4; ++mt)
            #pragma unroll
            for (int nt = 0; nt < 2; ++nt)
                acc[mt][nt] = __builtin_amdgcn_mfma_f32_16x16x32_f16(
                    af[mt], bf[nt], acc[mt][nt], 0, 0, 0);
        __syncthreads();
    }
    #pragma unroll
    for (int nt = 0; nt < 2; ++nt) {
        const int n = n0 + 32 * nh + 16 * nt + lo;
        const float bv = bias[n];
        #pragma unroll
        for (int mt = 0; mt < 4; ++mt) {
            const int m = m0 + 64 * mh + 16 * mt + 4 * qd;
            #pragma unroll
            for (int r = 0; r < 4; ++r)
                storeC(C + (size_t)(m + r) * N + n, acc[mt][nt][r] + bv);
        }
    }
}

// ---------------------------------------------------------------------------
// Kernel 5: recurrence — 8 WAVES, ONE barrier, wave-local h, TLP=2/SIMD.
// 64 WGs x 512 threads. Ladder evidence: baseline 8w/2bar=1183; R11
// 4w/1bar=1092 (only -91us: dropping to 1 wave/SIMD lost TLP latency
// hiding); R13 shfl butterfly=1367 (shfl = LDS-pipe op, longer chain).
// This shape combines the proven pieces: ONE lgkm-only barrier (R11) +
// 2 waves/SIMD (baseline's TLP) + wave-local h (R11):
//  * wave q: k-slice cols [32q,32q+32); lane l owns rows 4l..4l+3
//    (W frag 4x16 f16x2 = 64 VGPRs).
//  * phase 1: 4 uniform b128 reads of hx[p] slice [32q,+32) + 64 fdot2 +
//    1 b128 ps write. ps[2][8][HH] dbuf (16 KB).
//  * BARRIER (lgkm-only), then phase 2: wave q owns elements [32q,+32) —
//    lane l<32 computes element e=32q+l EXACTLY ONCE (8 b32 ps reads,
//    7 adds, tanh), writes hx[p^1][e] as b16 (WAVE-LOCAL: next step's
//    dot of wave q reads exactly this slice; in-wave DS order, no 2nd
//    barrier). Lanes 32-63 idle through phase 2 (~40cy issue cost).
//  * 2 waves/SIMD: one wave's ps-read/tanh latency hides under the
//    other's 64-fdot2 issue — the mechanism R11 gave up.
//  * ps[p] reuse at s+2 ordered by barrier(s+1) lgkm drain (R3-proven).
//  * per-SIMD issue ~424cy, chain ~700cy, 2-deep overlap -> ~900-1000cy
//    vs R11's measured 1280.
// R8: coverage = every wave spans all 256 rows x its k-slice. R9: operand
// pairing w2[r][4g+c] <-> hb[g].{x,y,z,w}. R13: NO shfl on the chain.
// ---------------------------------------------------------------------------
__global__ __launch_bounds__(512, 1) void recur_kernel(
    const float* __restrict__ Wm,              // [256][256] f32 row-major
    const __half* __restrict__ xp,             // [B][T][256] f16
    __half* __restrict__ hall)                 // [B][T][256] f16
{
    const int b = blockIdx.x;
    const int tid = threadIdx.x;
    const int l = tid & 63;
    const int q = tid >> 6;        // wave 0..7

    __shared__ float ps[2][8][HH];                    // dbuf partials, 16 KB
    __shared__ __align__(16) _Float16 hx[2][HH];      // dbuf packed h, 1 KB

    // W fragment: rows 4l..4l+3, cols [32q,32q+32) as f16 pairs (64 VGPRs).
    f16x2 w2[4][16];
    #pragma unroll
    for (int r = 0; r < 4; ++r) {
        const float* Wp = Wm + (size_t)(4 * l + r) * HH + 32 * q;
        #pragma unroll
        for (int c4 = 0; c4 < 8; ++c4) {
            float4 f = *(const float4*)(Wp + 4 * c4);
            w2[r][2 * c4 + 0] = f16x2{(_Float16)f.x, (_Float16)f.y};
            w2[r][2 * c4 + 1] = f16x2{(_Float16)f.z, (_Float16)f.w};
        }
    }
    if (tid < HH / 2) ((unsigned int*)&hx[0][0])[tid] = 0u;   // zero hx[0]
    __syncthreads();

    // Phase-2 element for this thread (lanes 32-63 mirror; writes masked).
    const int e = 32 * q + (l & 31);
    const bool st = (l < 32);
    const _Float16* xph = (const _Float16*)xp + (size_t)b * TT * HH + e;
    unsigned short* hw = (unsigned short*)hall + (size_t)b * TT * HH + e;

    _Float16 xpc[RCH], xpn[RCH], hst[RCH];
    #pragma unroll
    for (int s = 0; s < RCH; ++s) xpc[s] = xph[(size_t)s * HH];

    const int nch = TT / RCH;
    for (int c = 0; c < nch; ++c) {
        if (c + 1 < nch) {
            const _Float16* xn = xph + (size_t)(c + 1) * RCH * HH;
            #pragma unroll
            for (int s = 0; s < RCH; ++s) xpn[s] = xn[(size_t)s * HH];
        }
        #pragma unroll
        for (int s = 0; s < RCH; ++s) {
            const int p = s & 1;
            // --- phase 1: dot over own k-slice; h from hx[p] (broadcast) ---
            const uint4* hbp = (const uint4*)&hx[p][32 * q];
            uint4 hb[4];
            #pragma unroll
            for (int g = 0; g < 4; ++g) hb[g] = hbp[g];
            float a0 = 0.f, a1 = 0.f, a2 = 0.f, a3 = 0.f;
            #pragma unroll
            for (int g = 0; g < 4; ++g) {
                const f16x2 hp0 = u2h(hb[g].x), hp1 = u2h(hb[g].y);
                const f16x2 hp2 = u2h(hb[g].z), hp3 = u2h(hb[g].w);
                a0 = fdot2(w2[0][4 * g + 0], hp0, a0);
                a1 = fdot2(w2[1][4 * g + 0], hp0, a1);
                a2 = fdot2(w2[2][4 * g + 0], hp0, a2);
                a3 = fdot2(w2[3][4 * g + 0], hp0, a3);
                a0 = fdot2(w2[0][4 * g + 1], hp1, a0);
                a1 = fdot2(w2[1][4 * g + 1], hp1, a1);
                a2 = fdot2(w2[2][4 * g + 1], hp1, a2);
                a3 = fdot2(w2[3][4 * g + 1], hp1, a3);
                a0 = fdot2(w2[0][4 * g + 2], hp2, a0);
                a1 = fdot2(w2[1][4 * g + 2], hp2, a1);
                a2 = fdot2(w2[2][4 * g + 2], hp2, a2);
                a3 = fdot2(w2[3][4 * g + 2], hp2, a3);
                a0 = fdot2(w2[0][4 * g + 3], hp3, a0);
                a1 = fdot2(w2[1][4 * g + 3], hp3, a1);
                a2 = fdot2(w2[2][4 * g + 3], hp3, a2);
                a3 = fdot2(w2[3][4 * g + 3], hp3, a3);
            }
            *(float4*)&ps[p][q][4 * l] = make_float4(a0, a1, a2, a3);
            step_barrier();

            // --- phase 2: element e (exactly once; lanes>=32 mirror compute,
            //     masked write) ---
            float sum = ((ps[p][0][e] + ps[p][1][e]) + (ps[p][2][e] + ps[p][3][e]))
                      + ((ps[p][4][e] + ps[p][5][e]) + (ps[p][6][e] + ps[p][7][e]));
            float h = tanh_fast(sum + (float)xpc[s]);
            _Float16 hf = (_Float16)h;
            if (st) hx[p ^ 1][e] = hf;    // wave-local slice; in-wave DS order
            hst[s] = hf;
        }
        if (st) {
            unsigned short* hwc = hw + (size_t)c * RCH * HH;
            #pragma unroll
            for (int s2 = 0; s2 < RCH; ++s2)
                hwc[(size_t)s2 * HH] = __builtin_bit_cast(unsigned short, hst[s2]);
        }
        #pragma unroll
        for (int s2 = 0; s2 < RCH; ++s2) xpc[s2] = xpn[s2];
    }
}

// ---------------------------------------------------------------------------
extern "C" void kernel_launch(void* const* d_in, const int* in_sizes, int n_in,
                              void* d_out, int out_size, void* d_ws, size_t ws_size,
                              hipStream_t stream) {
    const float* x     = (const float*)d_in[0];   // [B][T][I]
    const float* W_in  = (const float*)d_in[1];   // [H][I]
    const float* b_in  = (const float*)d_in[2];   // [H]
    const float* W_out = (const float*)d_in[3];   // [O][H]
    const float* b_out = (const float*)d_in[4];   // [O]
    const float* u_raw = (const float*)d_in[5];   // [M][H]
    const float* sig   = (const float*)d_in[6];   // [H]
    const float* v_raw = (const float*)d_in[7];   // [M][H]
    float* out = (float*)d_out;                   // [B][T][O]

    char* ws = (char*)d_ws;
    size_t off = 0;
    auto alloc = [&](size_t bytes) -> void* {
        void* p = (void*)(ws + off);
        off += (bytes + 255) & ~((size_t)255);
        return p;
    };
    float* u_eff  = (float*)alloc((size_t)HH * HH * 4);
    float* v_eff  = (float*)alloc((size_t)HH * HH * 4);
    float* beta_u = (float*)alloc((size_t)HH * 4);
    float* beta_v = (float*)alloc((size_t)HH * 4);
    float* Ucol   = (float*)alloc((size_t)HH * HH * 4);
    float* Vrow   = (float*)alloc((size_t)HH * HH * 4);
    float* Wm     = (float*)alloc((size_t)HH * HH * 4);
    __half* xpbuf = (__half*)alloc((size_t)BB * TT * HH * 2);
    __half* hall  = (__half*)alloc((size_t)BB * TT * HH * 2);
    (void)ws_size; (void)in_sizes; (void)n_in; (void)out_size;

    prep_kernel<<<2 * HH, 64, 0, stream>>>(u_raw, v_raw, u_eff, v_eff, beta_u, beta_v);
    hh_kernel<<<(2 * HH) / 4, 256, 0, stream>>>(u_eff, v_eff, beta_u, beta_v, Ucol, Vrow);
    w_kernel<<<HH, HH, 0, stream>>>(Ucol, Vrow, sig, Wm);
    gemm_mfma<float, __half>
        <<<dim3((BB * TT) / 128, HH / 64), 256, 0, stream>>>(x, W_in, b_in, xpbuf, BB * TT, HH, II);
    recur_kernel<<<BB, 512, 0, stream>>>(Wm, xpbuf, hall);
    gemm_mfma<__half, float>
        <<<dim3((BB * TT) / 128, OO / 64), 256, 0, stream>>>(hall, W_out, b_out, out, BB * TT, OO, HH);
}